// Round 4
// baseline (301.204 us; speedup 1.0000x reference)
//
#include <hip/hip_runtime.h>
#include <hip/hip_bf16.h>
#include <math.h>

#define NNODES 50000
#define NEDGES 400000
// MUL0=16, MUL1=8, IN_DIM=40; w2 cols: w00 [0,256) w10 [256,320) w01 [320,448) w11 [448,576)
#define ALPHA0f    0.20412414523193154f   // sqrt(1/24) == ALPHA1*INV_SQRT3
#define INV_SQRT3f 0.57735026918962576f

typedef short bf16x8 __attribute__((ext_vector_type(8)));
typedef float f32x4  __attribute__((ext_vector_type(4)));

__device__ __forceinline__ short f2bf(float x) {
    __hip_bfloat16 h = __float2bfloat16(x);
    return *reinterpret_cast<short*>(&h);
}

__device__ __forceinline__ float softplus_f(float x) {
    return fmaxf(x, 0.0f) + log1pf(expf(-fabsf(x)));
}

// Transposed MFMA scheme: D = A*B with A = W^T tile (rows = weight cols),
// B = data^T (cols = edges). D-fragment: lane holds col = lane&15 = ITS OWN EDGE,
// rows = (lane>>4)*4 + r = weight-col indices. All per-edge factors are lane-local.
// MODE 0: atomic scatter fallback. MODE 1: store tp rows at perm[e] (CSR order).
template<int MODE>
__global__ __launch_bounds__(512)
void tp_mfma_kernel(const float* __restrict__ node_attr,
                    const int*   __restrict__ edge_index,
                    const float* __restrict__ edge_attr,
                    const float* __restrict__ edge_sh,
                    const float* __restrict__ w1,
                    const float* __restrict__ b1,
                    const float* __restrict__ w2,
                    const float* __restrict__ b2,
                    const int*   __restrict__ perm,    // MODE1
                    float* __restrict__ tp_out,        // MODE1
                    float* __restrict__ summed,        // MODE0
                    float* __restrict__ counts)        // MODE0
{
    __shared__ short w2f[36 * 512];      // A-fragments of W2^T tiles
    __shared__ short w1f[2 * 512];       // A-fragments of W1^T tiles
    __shared__ float b1s[32];
    __shared__ float b2s[576];
    __shared__ float xs[8][16][44];      // per-wave: node rows [40] + sh [40..43]
    __shared__ short hs[8][16][56];      // per-wave: h rows (bf16), padded for 2-way banks
    __shared__ int   dsts[8][16];

    const int tid = threadIdx.x;

    for (int i = tid; i < 36 * 512; i += 512) {
        int col = i % 576, k = i / 576;
        int t = col >> 4, lr = col & 15, lg = k >> 3, j = k & 7;
        w2f[((t * 64 + (lr | (lg << 4))) * 8) + j] = f2bf(w2[i]);
    }
    for (int i = tid; i < 1024; i += 512) {
        int col = i & 31, k = i >> 5;
        int t = col >> 4, lr = col & 15, lg = k >> 3, j = k & 7;
        w1f[((t * 64 + (lr | (lg << 4))) * 8) + j] = f2bf(w1[i]);
    }
    if (tid < 32) b1s[tid] = b1[tid];
    for (int i = tid; i < 576; i += 512) b2s[i] = b2[i];
    __syncthreads();

    const int wid  = tid >> 6, lane = tid & 63;
    const int lrow = lane & 15, lgrp = lane >> 4;
    const int upar = lgrp >> 1;          // u-parity handled by this lane (w10/w01)

    const bf16x8 w1a0 = *reinterpret_cast<const bf16x8*>(&w1f[lane * 8]);
    const bf16x8 w1a1 = *reinterpret_cast<const bf16x8*>(&w1f[512 + lane * 8]);
    const f32x4 b1c0 = *reinterpret_cast<const f32x4*>(&b1s[lgrp * 4]);
    const f32x4 b1c1 = *reinterpret_cast<const f32x4*>(&b1s[16 + lgrp * 4]);
    const f32x4 zero = {0.f, 0.f, 0.f, 0.f};

    for (int g = blockIdx.x; g < NEDGES / 128; g += gridDim.x) {
        const int e0 = g * 128 + wid * 16;

        if (lane < 16) {
            int d = edge_index[NEDGES + e0 + lane];
            dsts[wid][lane] = d;
            float4 sh = *(const float4*)(edge_sh + (size_t)(e0 + lane) * 4);
            xs[wid][lane][40] = sh.x; xs[wid][lane][41] = sh.y;
            xs[wid][lane][42] = sh.z; xs[wid][lane][43] = sh.w;
        }
        #pragma unroll
        for (int it = 0; it < 3; ++it) {
            int idx = it * 64 + lane;
            if (idx < 160) {
                int ed = idx / 10, part = idx % 10;
                int d = dsts[wid][ed];
                float4 v = *(const float4*)(node_attr + (size_t)d * 40 + part * 4);
                *(float4*)&xs[wid][ed][part * 4] = v;
            }
        }

        // ---- GEMM1 (transposed): D1 = W1^T * EA^T + b1 ; lane col = edge lrow ----
        const float4* ear = (const float4*)(edge_attr + (size_t)(e0 + lrow) * 32 + lgrp * 8);
        float4 ea0 = ear[0], ea1 = ear[1];
        bf16x8 bfrag;
        bfrag[0] = f2bf(ea0.x); bfrag[1] = f2bf(ea0.y); bfrag[2] = f2bf(ea0.z); bfrag[3] = f2bf(ea0.w);
        bfrag[4] = f2bf(ea1.x); bfrag[5] = f2bf(ea1.y); bfrag[6] = f2bf(ea1.z); bfrag[7] = f2bf(ea1.w);
        f32x4 c0 = __builtin_amdgcn_mfma_f32_16x16x32_bf16(w1a0, bfrag, b1c0, 0, 0, 0);
        f32x4 c1 = __builtin_amdgcn_mfma_f32_16x16x32_bf16(w1a1, bfrag, b1c1, 0, 0, 0);
        // lane holds h[e=lrow][j = lgrp*4+r] (c0) and [16+lgrp*4+r] (c1)
        {
            short4 p0, p1;
            p0.x = f2bf(softplus_f(c0[0])); p0.y = f2bf(softplus_f(c0[1]));
            p0.z = f2bf(softplus_f(c0[2])); p0.w = f2bf(softplus_f(c0[3]));
            p1.x = f2bf(softplus_f(c1[0])); p1.y = f2bf(softplus_f(c1[1]));
            p1.z = f2bf(softplus_f(c1[2])); p1.w = f2bf(softplus_f(c1[3]));
            *(short4*)&hs[wid][lrow][lgrp * 4]      = p0;
            *(short4*)&hs[wid][lrow][16 + lgrp * 4] = p1;
        }
        // B-fragment of H^T: lane needs h[lrow][lgrp*8 .. +7]
        const bf16x8 hfrag = *reinterpret_cast<const bf16x8*>(&hs[wid][lrow][lgrp * 8]);

        // per-lane (edge lrow) constants
        const float y0  = xs[wid][lrow][40];
        const float y1x = xs[wid][lrow][41];
        const float y1y = xs[wid][lrow][42];
        const float y1z = xs[wid][lrow][43];

        f32x4 acc0 = zero, am0 = zero, am1 = zero, am2 = zero, r01 = zero;

        // ---- w00 (tiles 0..15): lane rows = cols u*16+w, u=t, w=lgrp*4+r ----
        #pragma unroll
        for (int t = 0; t < 16; ++t) {
            bf16x8 wa = *reinterpret_cast<const bf16x8*>(&w2f[(t * 64 + lane) * 8]);
            f32x4 b2c = *reinterpret_cast<const f32x4*>(&b2s[t * 16 + lgrp * 4]);
            f32x4 wv = __builtin_amdgcn_mfma_f32_16x16x32_bf16(wa, hfrag, b2c, 0, 0, 0);
            float F = xs[wid][lrow][t] * y0;
            acc0 += wv * F;
        }
        // ---- w10 (tiles 16..19): u = 2*tt+upar, w = (lgrp&1)*4+r ----
        #pragma unroll
        for (int tt = 0; tt < 4; ++tt) {
            int t = 16 + tt;
            bf16x8 wa = *reinterpret_cast<const bf16x8*>(&w2f[(t * 64 + lane) * 8]);
            f32x4 b2c = *reinterpret_cast<const f32x4*>(&b2s[t * 16 + lgrp * 4]);
            f32x4 wv = __builtin_amdgcn_mfma_f32_16x16x32_bf16(wa, hfrag, b2c, 0, 0, 0);
            int u = 2 * tt + upar;
            float f0 = y0 * xs[wid][lrow][16 + u * 3 + 0];
            float f1 = y0 * xs[wid][lrow][16 + u * 3 + 1];
            float f2 = y0 * xs[wid][lrow][16 + u * 3 + 2];
            am0 += wv * f0; am1 += wv * f1; am2 += wv * f2;
        }
        // ---- w01 (tiles 20..27): u = 2*tt+upar, w = (lgrp&1)*4+r ----
        #pragma unroll
        for (int tt = 0; tt < 8; ++tt) {
            int t = 20 + tt;
            bf16x8 wa = *reinterpret_cast<const bf16x8*>(&w2f[(t * 64 + lane) * 8]);
            f32x4 b2c = *reinterpret_cast<const f32x4*>(&b2s[t * 16 + lgrp * 4]);
            f32x4 wv = __builtin_amdgcn_mfma_f32_16x16x32_bf16(wa, hfrag, b2c, 0, 0, 0);
            int u = 2 * tt + upar;
            float s = xs[wid][lrow][u];
            r01 += wv * s;
        }
        // ---- w11 (tiles 28..35): u = tt, w = lgrp*4+r (same acc0) ----
        #pragma unroll
        for (int tt = 0; tt < 8; ++tt) {
            int t = 28 + tt;
            bf16x8 wa = *reinterpret_cast<const bf16x8*>(&w2f[(t * 64 + lane) * 8]);
            f32x4 b2c = *reinterpret_cast<const f32x4*>(&b2s[t * 16 + lgrp * 4]);
            f32x4 wv = __builtin_amdgcn_mfma_f32_16x16x32_bf16(wa, hfrag, b2c, 0, 0, 0);
            float bu = INV_SQRT3f * (xs[wid][lrow][16 + tt * 3 + 0] * y1x +
                                     xs[wid][lrow][16 + tt * 3 + 1] * y1y +
                                     xs[wid][lrow][16 + tt * 3 + 2] * y1z);
            acc0 += wv * bu;
        }

        // ---- combine u-parities: lanes l and l^32 share w, complementary u ----
        #pragma unroll
        for (int r = 0; r < 4; ++r) {
            am0[r] += __shfl_xor(am0[r], 32);
            am1[r] += __shfl_xor(am1[r], 32);
            am2[r] += __shfl_xor(am2[r], 32);
            r01[r] += __shfl_xor(r01[r], 32);
        }

        float4 q0, q1, q2;
        {
            float o1[12];
            #pragma unroll
            for (int r = 0; r < 4; ++r) {
                o1[r * 3 + 0] = ALPHA0f * (am0[r] + y1x * r01[r]);
                o1[r * 3 + 1] = ALPHA0f * (am1[r] + y1y * r01[r]);
                o1[r * 3 + 2] = ALPHA0f * (am2[r] + y1z * r01[r]);
            }
            q0.x = o1[0]; q0.y = o1[1]; q0.z = o1[2];  q0.w = o1[3];
            q1.x = o1[4]; q1.y = o1[5]; q1.z = o1[6];  q1.w = o1[7];
            q2.x = o1[8]; q2.y = o1[9]; q2.z = o1[10]; q2.w = o1[11];
        }
        float4 p0;
        p0.x = ALPHA0f * acc0[0]; p0.y = ALPHA0f * acc0[1];
        p0.z = ALPHA0f * acc0[2]; p0.w = ALPHA0f * acc0[3];

        if (MODE == 1) {
            const int pe = perm[e0 + lrow];
            float* row = tp_out + (size_t)pe * 40;
            *(float4*)(row + lgrp * 4) = p0;           // out0: w = lgrp*4+r
            if (lgrp < 2) {                            // out1: 12 contiguous floats
                float* r1 = row + 16 + lgrp * 12;
                *(float4*)(r1 + 0) = q0;
                *(float4*)(r1 + 4) = q1;
                *(float4*)(r1 + 8) = q2;
            }
        } else {
            const int src = edge_index[e0 + lrow];
            float* row = summed + (size_t)src * 40;
            atomicAdd(row + lgrp * 4 + 0, p0.x);
            atomicAdd(row + lgrp * 4 + 1, p0.y);
            atomicAdd(row + lgrp * 4 + 2, p0.z);
            atomicAdd(row + lgrp * 4 + 3, p0.w);
            if (lgrp < 2) {
                float* r1 = row + 16 + lgrp * 12;
                atomicAdd(r1 + 0,  q0.x); atomicAdd(r1 + 1,  q0.y);
                atomicAdd(r1 + 2,  q0.z); atomicAdd(r1 + 3,  q0.w);
                atomicAdd(r1 + 4,  q1.x); atomicAdd(r1 + 5,  q1.y);
                atomicAdd(r1 + 6,  q1.z); atomicAdd(r1 + 7,  q1.w);
                atomicAdd(r1 + 8,  q2.x); atomicAdd(r1 + 9,  q2.y);
                atomicAdd(r1 + 10, q2.z); atomicAdd(r1 + 11, q2.w);
            }
            if (lgrp == 0) atomicAdd(&counts[src], 1.0f);
        }
    }
}

extern "C" __global__ __launch_bounds__(256)
void hist_kernel(const int* __restrict__ edge_index, int* __restrict__ counts_i)
{
    int e = blockIdx.x * 256 + threadIdx.x;
    if (e < NEDGES) atomicAdd(&counts_i[edge_index[e]], 1);
}

extern "C" __global__ __launch_bounds__(256)
void scanA_kernel(const int* __restrict__ counts_i, int* __restrict__ offsets,
                  int* __restrict__ bsums)
{
    __shared__ int s[256];
    int t = threadIdx.x, id = blockIdx.x * 256 + t;
    int c = (id < NNODES) ? counts_i[id] : 0;
    s[t] = c; __syncthreads();
    #pragma unroll
    for (int off = 1; off < 256; off <<= 1) {
        int v = (t >= off) ? s[t - off] : 0;
        __syncthreads();
        s[t] += v;
        __syncthreads();
    }
    if (id < NNODES) offsets[id] = s[t] - c;
    if (t == 255) bsums[blockIdx.x] = s[255];
}

extern "C" __global__ __launch_bounds__(256)
void scanB_kernel(int* __restrict__ bsums, int nblocks)
{
    __shared__ int s[256];
    int t = threadIdx.x;
    int c = (t < nblocks) ? bsums[t] : 0;
    s[t] = c; __syncthreads();
    #pragma unroll
    for (int off = 1; off < 256; off <<= 1) {
        int v = (t >= off) ? s[t - off] : 0;
        __syncthreads();
        s[t] += v;
        __syncthreads();
    }
    if (t < nblocks) bsums[t] = s[t] - c;
}

extern "C" __global__ __launch_bounds__(256)
void scanC_kernel(int* __restrict__ offsets, const int* __restrict__ bsums,
                  int* __restrict__ cursor)
{
    int id = blockIdx.x * 256 + threadIdx.x;
    if (id < NNODES) {
        int o = offsets[id] + bsums[id >> 8];
        offsets[id] = o;
        cursor[id] = o;
    }
}

extern "C" __global__ __launch_bounds__(256)
void scatter_perm_kernel(const int* __restrict__ edge_index, int* __restrict__ cursor,
                         int* __restrict__ perm)
{
    int e = blockIdx.x * 256 + threadIdx.x;
    if (e < NEDGES) {
        int src = edge_index[e];
        perm[e] = atomicAdd(&cursor[src], 1);
    }
}

// segmented mean over CONTIGUOUS tp rows + residual; one wave per node
extern "C" __global__ __launch_bounds__(256)
void gather_kernel(const float* __restrict__ tp, const int* __restrict__ offsets,
                   const float* __restrict__ node_attr, float* __restrict__ out)
{
    int gw = (blockIdx.x * 256 + threadIdx.x) >> 6;
    int lane = threadIdx.x & 63;
    int nwaves = (gridDim.x * 256) >> 6;
    for (int n = gw; n < NNODES; n += nwaves) {
        int start = offsets[n];
        int end = (n + 1 < NNODES) ? offsets[n + 1] : NEDGES;
        if (lane < 40) {
            float acc = 0.0f, acc2 = 0.0f;
            int i = start;
            for (; i + 2 <= end; i += 2) {
                acc  += tp[(size_t)i * 40 + lane];
                acc2 += tp[(size_t)(i + 1) * 40 + lane];
            }
            if (i < end) acc += tp[(size_t)i * 40 + lane];
            float deg = (float)(end - start);
            out[(size_t)n * 40 + lane] =
                (acc + acc2) / fmaxf(deg, 1.0f) + node_attr[(size_t)n * 40 + lane];
        }
    }
}

extern "C" __global__ __launch_bounds__(256)
void finalize_kernel(const float* __restrict__ summed,
                     const float* __restrict__ counts,
                     const float* __restrict__ node_attr,
                     float* __restrict__ out)
{
    int idx = blockIdx.x * 256 + threadIdx.x;
    if (idx < NNODES * 40) {
        int n = idx / 40;
        float c = fmaxf(counts[n], 1.0f);
        out[idx] = summed[idx] / c + node_attr[idx];
    }
}

extern "C" void kernel_launch(void* const* d_in, const int* in_sizes, int n_in,
                              void* d_out, int out_size, void* d_ws, size_t ws_size,
                              hipStream_t stream)
{
    const float* node_attr  = (const float*)d_in[0];
    const int*   edge_index = (const int*)  d_in[1];
    const float* edge_attr  = (const float*)d_in[2];
    const float* edge_sh    = (const float*)d_in[3];
    const float* w1 = (const float*)d_in[4];
    const float* b1 = (const float*)d_in[5];
    const float* w2 = (const float*)d_in[6];
    const float* b2 = (const float*)d_in[7];
    float* out = (float*)d_out;

    const int SCAN_BLOCKS = (NNODES + 255) / 256;   // 196
    const int EDGE_BLOCKS = (NEDGES + 255) / 256;   // 1563
    const size_t NEED = ((size_t)NEDGES * 40 + NEDGES + 3 * (size_t)NNODES + 256) * 4;

    if (ws_size >= NEED) {
        float* tp       = (float*)d_ws;                     // NEDGES*40
        int*   counts_i = (int*)(tp + (size_t)NEDGES * 40); // NNODES
        int*   offsets  = counts_i + NNODES;                // NNODES
        int*   cursor   = offsets + NNODES;                 // NNODES
        int*   perm     = cursor + NNODES;                  // NEDGES
        int*   bsums    = perm + NEDGES;                    // 256

        hipMemsetAsync(counts_i, 0, (size_t)NNODES * 4, stream);

        hipLaunchKernelGGL(hist_kernel, dim3(EDGE_BLOCKS), dim3(256), 0, stream,
                           edge_index, counts_i);
        hipLaunchKernelGGL(scanA_kernel, dim3(SCAN_BLOCKS), dim3(256), 0, stream,
                           counts_i, offsets, bsums);
        hipLaunchKernelGGL(scanB_kernel, dim3(1), dim3(256), 0, stream,
                           bsums, SCAN_BLOCKS);
        hipLaunchKernelGGL(scanC_kernel, dim3(SCAN_BLOCKS), dim3(256), 0, stream,
                           offsets, bsums, cursor);
        hipLaunchKernelGGL(scatter_perm_kernel, dim3(EDGE_BLOCKS), dim3(256), 0, stream,
                           edge_index, cursor, perm);

        hipLaunchKernelGGL((tp_mfma_kernel<1>), dim3(512), dim3(512), 0, stream,
                           node_attr, edge_index, edge_attr, edge_sh, w1, b1, w2, b2,
                           perm, tp, (float*)nullptr, (float*)nullptr);

        hipLaunchKernelGGL(gather_kernel, dim3(2048), dim3(256), 0, stream,
                           tp, offsets, node_attr, out);
    } else {
        float* summed = (float*)d_ws;
        float* counts = summed + (size_t)NNODES * 40;
        hipMemsetAsync(d_ws, 0, (size_t)(NNODES * 40 + NNODES) * sizeof(float), stream);
        hipLaunchKernelGGL((tp_mfma_kernel<0>), dim3(512), dim3(512), 0, stream,
                           node_attr, edge_index, edge_attr, edge_sh, w1, b1, w2, b2,
                           (int*)nullptr, (float*)nullptr, summed, counts);
        int fblk = (NNODES * 40 + 255) / 256;
        hipLaunchKernelGGL(finalize_kernel, dim3(fblk), dim3(256), 0, stream,
                           summed, counts, node_attr, out);
    }
}

// Round 5
// 292.555 us; speedup vs baseline: 1.0296x; 1.0296x over previous
//
#include <hip/hip_runtime.h>
#include <hip/hip_bf16.h>
#include <math.h>

#define NNODES 50000
#define NEDGES 400000
// MUL0=16, MUL1=8, IN_DIM=40; w2 cols: w00 [0,256) w10 [256,320) w01 [320,448) w11 [448,576)
#define ALPHA0f    0.20412414523193154f   // sqrt(1/24) == ALPHA1*INV_SQRT3
#define INV_SQRT3f 0.57735026918962576f
#define TPROW      64                     // padded tp row: 64 bf16 = 128 B = one cache line

typedef short bf16x8 __attribute__((ext_vector_type(8)));
typedef float f32x4  __attribute__((ext_vector_type(4)));

__device__ __forceinline__ short f2bf(float x) {
    __hip_bfloat16 h = __float2bfloat16(x);
    return *reinterpret_cast<short*>(&h);
}
__device__ __forceinline__ float bf2f(unsigned short x) {
    return __uint_as_float(((unsigned)x) << 16);
}
__device__ __forceinline__ float softplus_f(float x) {
    return fmaxf(x, 0.0f) + log1pf(expf(-fabsf(x)));
}

// Transposed MFMA: D = A*B, A = W^T tile (rows = weight cols), B = data^T (cols = edges).
// D-fragment: lane's col (lane&15) = ITS OWN EDGE; rows (lane>>4)*4+r = weight cols.
// MODE 0: atomic-scatter fallback. MODE 1: bf16 tp rows, edge-ordered, 128B-padded, full-line writes.
template<int MODE>
__global__ __launch_bounds__(512)
void tp_mfma_kernel(const float* __restrict__ node_attr,
                    const int*   __restrict__ edge_index,
                    const float* __restrict__ edge_attr,
                    const float* __restrict__ edge_sh,
                    const float* __restrict__ w1,
                    const float* __restrict__ b1,
                    const float* __restrict__ w2,
                    const float* __restrict__ b2,
                    unsigned short* __restrict__ tp_out, // MODE1
                    int*   __restrict__ counts_i,        // MODE1
                    float* __restrict__ summed,          // MODE0
                    float* __restrict__ counts)          // MODE0
{
    __shared__ short w2f[36 * 512];      // A-fragments of W2^T tiles
    __shared__ short w1f[2 * 512];
    __shared__ float b1s[32];
    __shared__ float b2s[576];
    __shared__ float xs[8][16][44];      // node rows [40] + sh [40..43]
    __shared__ short hs[8][16][56];
    __shared__ int   dsts[8][16];

    const int tid = threadIdx.x;

    for (int i = tid; i < 36 * 512; i += 512) {
        int col = i % 576, k = i / 576;
        int t = col >> 4, lr = col & 15, lg = k >> 3, j = k & 7;
        w2f[((t * 64 + (lr | (lg << 4))) * 8) + j] = f2bf(w2[i]);
    }
    for (int i = tid; i < 1024; i += 512) {
        int col = i & 31, k = i >> 5;
        int t = col >> 4, lr = col & 15, lg = k >> 3, j = k & 7;
        w1f[((t * 64 + (lr | (lg << 4))) * 8) + j] = f2bf(w1[i]);
    }
    if (tid < 32) b1s[tid] = b1[tid];
    for (int i = tid; i < 576; i += 512) b2s[i] = b2[i];
    __syncthreads();

    const int wid  = tid >> 6, lane = tid & 63;
    const int lrow = lane & 15, lgrp = lane >> 4;
    const int upar = lgrp >> 1;

    const bf16x8 w1a0 = *reinterpret_cast<const bf16x8*>(&w1f[lane * 8]);
    const bf16x8 w1a1 = *reinterpret_cast<const bf16x8*>(&w1f[512 + lane * 8]);
    const f32x4 b1c0 = *reinterpret_cast<const f32x4*>(&b1s[lgrp * 4]);
    const f32x4 b1c1 = *reinterpret_cast<const f32x4*>(&b1s[16 + lgrp * 4]);
    const f32x4 zero = {0.f, 0.f, 0.f, 0.f};

    for (int g = blockIdx.x; g < NEDGES / 128; g += gridDim.x) {
        const int e0 = g * 128 + wid * 16;

        if (lane < 16) {
            int d = edge_index[NEDGES + e0 + lane];
            dsts[wid][lane] = d;
            float4 sh = *(const float4*)(edge_sh + (size_t)(e0 + lane) * 4);
            xs[wid][lane][40] = sh.x; xs[wid][lane][41] = sh.y;
            xs[wid][lane][42] = sh.z; xs[wid][lane][43] = sh.w;
        }
        #pragma unroll
        for (int it = 0; it < 3; ++it) {
            int idx = it * 64 + lane;
            if (idx < 160) {
                int ed = idx / 10, part = idx % 10;
                int d = dsts[wid][ed];
                float4 v = *(const float4*)(node_attr + (size_t)d * 40 + part * 4);
                *(float4*)&xs[wid][ed][part * 4] = v;
            }
        }

        // ---- GEMM1 (transposed): D1 = W1^T * EA^T + b1 ----
        const float4* ear = (const float4*)(edge_attr + (size_t)(e0 + lrow) * 32 + lgrp * 8);
        float4 ea0 = ear[0], ea1 = ear[1];
        bf16x8 bfrag;
        bfrag[0] = f2bf(ea0.x); bfrag[1] = f2bf(ea0.y); bfrag[2] = f2bf(ea0.z); bfrag[3] = f2bf(ea0.w);
        bfrag[4] = f2bf(ea1.x); bfrag[5] = f2bf(ea1.y); bfrag[6] = f2bf(ea1.z); bfrag[7] = f2bf(ea1.w);
        f32x4 c0 = __builtin_amdgcn_mfma_f32_16x16x32_bf16(w1a0, bfrag, b1c0, 0, 0, 0);
        f32x4 c1 = __builtin_amdgcn_mfma_f32_16x16x32_bf16(w1a1, bfrag, b1c1, 0, 0, 0);
        {
            short4 p0, p1;
            p0.x = f2bf(softplus_f(c0[0])); p0.y = f2bf(softplus_f(c0[1]));
            p0.z = f2bf(softplus_f(c0[2])); p0.w = f2bf(softplus_f(c0[3]));
            p1.x = f2bf(softplus_f(c1[0])); p1.y = f2bf(softplus_f(c1[1]));
            p1.z = f2bf(softplus_f(c1[2])); p1.w = f2bf(softplus_f(c1[3]));
            *(short4*)&hs[wid][lrow][lgrp * 4]      = p0;
            *(short4*)&hs[wid][lrow][16 + lgrp * 4] = p1;
        }
        const bf16x8 hfrag = *reinterpret_cast<const bf16x8*>(&hs[wid][lrow][lgrp * 8]);

        const float y0  = xs[wid][lrow][40];
        const float y1x = xs[wid][lrow][41];
        const float y1y = xs[wid][lrow][42];
        const float y1z = xs[wid][lrow][43];

        f32x4 acc0 = zero, am0 = zero, am1 = zero, am2 = zero, r01 = zero;

        // ---- w00 (tiles 0..15): u=t, w=lgrp*4+r ----
        #pragma unroll
        for (int t = 0; t < 16; ++t) {
            bf16x8 wa = *reinterpret_cast<const bf16x8*>(&w2f[(t * 64 + lane) * 8]);
            f32x4 b2c = *reinterpret_cast<const f32x4*>(&b2s[t * 16 + lgrp * 4]);
            f32x4 wv = __builtin_amdgcn_mfma_f32_16x16x32_bf16(wa, hfrag, b2c, 0, 0, 0);
            float F = xs[wid][lrow][t] * y0;
            acc0 += wv * F;
        }
        // ---- w10 (tiles 16..19): u = 2*tt+upar, w = (lgrp&1)*4+r ----
        #pragma unroll
        for (int tt = 0; tt < 4; ++tt) {
            int t = 16 + tt;
            bf16x8 wa = *reinterpret_cast<const bf16x8*>(&w2f[(t * 64 + lane) * 8]);
            f32x4 b2c = *reinterpret_cast<const f32x4*>(&b2s[t * 16 + lgrp * 4]);
            f32x4 wv = __builtin_amdgcn_mfma_f32_16x16x32_bf16(wa, hfrag, b2c, 0, 0, 0);
            int u = 2 * tt + upar;
            float f0 = y0 * xs[wid][lrow][16 + u * 3 + 0];
            float f1 = y0 * xs[wid][lrow][16 + u * 3 + 1];
            float f2 = y0 * xs[wid][lrow][16 + u * 3 + 2];
            am0 += wv * f0; am1 += wv * f1; am2 += wv * f2;
        }
        // ---- w01 (tiles 20..27): u = 2*tt+upar ----
        #pragma unroll
        for (int tt = 0; tt < 8; ++tt) {
            int t = 20 + tt;
            bf16x8 wa = *reinterpret_cast<const bf16x8*>(&w2f[(t * 64 + lane) * 8]);
            f32x4 b2c = *reinterpret_cast<const f32x4*>(&b2s[t * 16 + lgrp * 4]);
            f32x4 wv = __builtin_amdgcn_mfma_f32_16x16x32_bf16(wa, hfrag, b2c, 0, 0, 0);
            int u = 2 * tt + upar;
            float s = xs[wid][lrow][u];
            r01 += wv * s;
        }
        // ---- w11 (tiles 28..35): u = tt, w = lgrp*4+r ----
        #pragma unroll
        for (int tt = 0; tt < 8; ++tt) {
            int t = 28 + tt;
            bf16x8 wa = *reinterpret_cast<const bf16x8*>(&w2f[(t * 64 + lane) * 8]);
            f32x4 b2c = *reinterpret_cast<const f32x4*>(&b2s[t * 16 + lgrp * 4]);
            f32x4 wv = __builtin_amdgcn_mfma_f32_16x16x32_bf16(wa, hfrag, b2c, 0, 0, 0);
            float bu = INV_SQRT3f * (xs[wid][lrow][16 + tt * 3 + 0] * y1x +
                                     xs[wid][lrow][16 + tt * 3 + 1] * y1y +
                                     xs[wid][lrow][16 + tt * 3 + 2] * y1z);
            acc0 += wv * bu;
        }

        // ---- combine u-parities (lanes l, l^32 share w) ----
        #pragma unroll
        for (int r = 0; r < 4; ++r) {
            am0[r] += __shfl_xor(am0[r], 32);
            am1[r] += __shfl_xor(am1[r], 32);
            am2[r] += __shfl_xor(am2[r], 32);
            r01[r] += __shfl_xor(r01[r], 32);
        }

        const float m1 = (lgrp < 2) ? ALPHA0f : 0.0f;  // pad lanes write zeros
        float o1[12];
        #pragma unroll
        for (int r = 0; r < 4; ++r) {
            o1[r * 3 + 0] = m1 * (am0[r] + y1x * r01[r]);
            o1[r * 3 + 1] = m1 * (am1[r] + y1y * r01[r]);
            o1[r * 3 + 2] = m1 * (am2[r] + y1z * r01[r]);
        }

        if (MODE == 1) {
            unsigned short* row = tp_out + (size_t)(e0 + lrow) * TPROW;
            short4 s0;
            s0.x = f2bf(ALPHA0f * acc0[0]); s0.y = f2bf(ALPHA0f * acc0[1]);
            s0.z = f2bf(ALPHA0f * acc0[2]); s0.w = f2bf(ALPHA0f * acc0[3]);
            *(short4*)(row + lgrp * 4) = s0;
            // out1 (lgrp 0,1) / zero padding (lgrp 2,3): elems 16 + lgrp*12 .. +11
            #pragma unroll
            for (int q = 0; q < 3; ++q) {
                short4 sq;
                sq.x = f2bf(o1[q * 4 + 0]); sq.y = f2bf(o1[q * 4 + 1]);
                sq.z = f2bf(o1[q * 4 + 2]); sq.w = f2bf(o1[q * 4 + 3]);
                *(short4*)(row + 16 + lgrp * 12 + q * 4) = sq;
            }
            if (lgrp == 0) atomicAdd(&counts_i[edge_index[e0 + lrow]], 1);
        } else {
            const int src = edge_index[e0 + lrow];
            float* row = summed + (size_t)src * 40;
            atomicAdd(row + lgrp * 4 + 0, ALPHA0f * acc0[0]);
            atomicAdd(row + lgrp * 4 + 1, ALPHA0f * acc0[1]);
            atomicAdd(row + lgrp * 4 + 2, ALPHA0f * acc0[2]);
            atomicAdd(row + lgrp * 4 + 3, ALPHA0f * acc0[3]);
            if (lgrp < 2) {
                float* r1 = row + 16 + lgrp * 12;
                #pragma unroll
                for (int q = 0; q < 12; ++q) atomicAdd(r1 + q, o1[q]);
            }
            if (lgrp == 0) atomicAdd(&counts[src], 1.0f);
        }
    }
}

extern "C" __global__ __launch_bounds__(256)
void scanA_kernel(const int* __restrict__ counts_i, int* __restrict__ offsets,
                  int* __restrict__ bsums)
{
    __shared__ int s[256];
    int t = threadIdx.x, id = blockIdx.x * 256 + t;
    int c = (id < NNODES) ? counts_i[id] : 0;
    s[t] = c; __syncthreads();
    #pragma unroll
    for (int off = 1; off < 256; off <<= 1) {
        int v = (t >= off) ? s[t - off] : 0;
        __syncthreads();
        s[t] += v;
        __syncthreads();
    }
    if (id < NNODES) offsets[id] = s[t] - c;
    if (t == 255) bsums[blockIdx.x] = s[255];
}

extern "C" __global__ __launch_bounds__(256)
void scanB_kernel(int* __restrict__ bsums, int nblocks)
{
    __shared__ int s[256];
    int t = threadIdx.x;
    int c = (t < nblocks) ? bsums[t] : 0;
    s[t] = c; __syncthreads();
    #pragma unroll
    for (int off = 1; off < 256; off <<= 1) {
        int v = (t >= off) ? s[t - off] : 0;
        __syncthreads();
        s[t] += v;
        __syncthreads();
    }
    if (t < nblocks) bsums[t] = s[t] - c;
}

extern "C" __global__ __launch_bounds__(256)
void scanC_kernel(int* __restrict__ offsets, const int* __restrict__ bsums,
                  int* __restrict__ cursor)
{
    int id = blockIdx.x * 256 + threadIdx.x;
    if (id < NNODES) {
        int o = offsets[id] + bsums[id >> 8];
        offsets[id] = o;
        cursor[id] = o;
    }
}

extern "C" __global__ __launch_bounds__(256)
void scatter_kernel(const int* __restrict__ edge_index, int* __restrict__ cursor,
                    int* __restrict__ csr)
{
    int e = blockIdx.x * 256 + threadIdx.x;
    if (e < NEDGES) {
        int src = edge_index[e];
        int pos = atomicAdd(&cursor[src], 1);
        csr[pos] = e;
    }
}

// segmented mean + residual; one wave per node; tp rows are single 128-B lines
extern "C" __global__ __launch_bounds__(256)
void gather_kernel(const unsigned short* __restrict__ tp, const int* __restrict__ offsets,
                   const int* __restrict__ csr, const float* __restrict__ node_attr,
                   float* __restrict__ out)
{
    int gw = (blockIdx.x * 256 + threadIdx.x) >> 6;
    int lane = threadIdx.x & 63;
    int nwaves = (gridDim.x * 256) >> 6;
    for (int n = gw; n < NNODES; n += nwaves) {
        int start = offsets[n];
        int end = (n + 1 < NNODES) ? offsets[n + 1] : NEDGES;
        float acc = 0.0f, acc2 = 0.0f;
        int i = start;
        for (; i + 2 <= end; i += 2) {
            int id0 = csr[i], id1 = csr[i + 1];      // uniform addr: broadcast
            if (lane < 40) {
                acc  += bf2f(tp[(size_t)id0 * TPROW + lane]);
                acc2 += bf2f(tp[(size_t)id1 * TPROW + lane]);
            }
        }
        if (i < end) {
            int id0 = csr[i];
            if (lane < 40) acc += bf2f(tp[(size_t)id0 * TPROW + lane]);
        }
        if (lane < 40) {
            float deg = (float)(end - start);
            out[(size_t)n * 40 + lane] =
                (acc + acc2) / fmaxf(deg, 1.0f) + node_attr[(size_t)n * 40 + lane];
        }
    }
}

extern "C" __global__ __launch_bounds__(256)
void finalize_kernel(const float* __restrict__ summed,
                     const float* __restrict__ counts,
                     const float* __restrict__ node_attr,
                     float* __restrict__ out)
{
    int idx = blockIdx.x * 256 + threadIdx.x;
    if (idx < NNODES * 40) {
        int n = idx / 40;
        float c = fmaxf(counts[n], 1.0f);
        out[idx] = summed[idx] / c + node_attr[idx];
    }
}

extern "C" void kernel_launch(void* const* d_in, const int* in_sizes, int n_in,
                              void* d_out, int out_size, void* d_ws, size_t ws_size,
                              hipStream_t stream)
{
    const float* node_attr  = (const float*)d_in[0];
    const int*   edge_index = (const int*)  d_in[1];
    const float* edge_attr  = (const float*)d_in[2];
    const float* edge_sh    = (const float*)d_in[3];
    const float* w1 = (const float*)d_in[4];
    const float* b1 = (const float*)d_in[5];
    const float* w2 = (const float*)d_in[6];
    const float* b2 = (const float*)d_in[7];
    float* out = (float*)d_out;

    const int SCAN_BLOCKS = (NNODES + 255) / 256;   // 196
    const int EDGE_BLOCKS = (NEDGES + 255) / 256;   // 1563
    const size_t NEED = (size_t)NEDGES * TPROW * 2 +
                        ((size_t)3 * NNODES + NEDGES + 256) * 4;

    if (ws_size >= NEED) {
        unsigned short* tp = (unsigned short*)d_ws;          // NEDGES*64 bf16 (128B rows)
        int* counts_i = (int*)(tp + (size_t)NEDGES * TPROW); // NNODES
        int* offsets  = counts_i + NNODES;                   // NNODES
        int* cursor   = offsets + NNODES;                    // NNODES
        int* csr      = cursor + NNODES;                     // NEDGES
        int* bsums    = csr + NEDGES;                        // 256

        hipMemsetAsync(counts_i, 0, (size_t)NNODES * 4, stream);

        hipLaunchKernelGGL((tp_mfma_kernel<1>), dim3(512), dim3(512), 0, stream,
                           node_attr, edge_index, edge_attr, edge_sh, w1, b1, w2, b2,
                           tp, counts_i, (float*)nullptr, (float*)nullptr);

        hipLaunchKernelGGL(scanA_kernel, dim3(SCAN_BLOCKS), dim3(256), 0, stream,
                           counts_i, offsets, bsums);
        hipLaunchKernelGGL(scanB_kernel, dim3(1), dim3(256), 0, stream,
                           bsums, SCAN_BLOCKS);
        hipLaunchKernelGGL(scanC_kernel, dim3(SCAN_BLOCKS), dim3(256), 0, stream,
                           offsets, bsums, cursor);
        hipLaunchKernelGGL(scatter_kernel, dim3(EDGE_BLOCKS), dim3(256), 0, stream,
                           edge_index, cursor, csr);
        hipLaunchKernelGGL(gather_kernel, dim3(2048), dim3(256), 0, stream,
                           tp, offsets, csr, node_attr, out);
    } else {
        float* summed = (float*)d_ws;
        float* counts = summed + (size_t)NNODES * 40;
        hipMemsetAsync(d_ws, 0, (size_t)(NNODES * 40 + NNODES) * sizeof(float), stream);
        hipLaunchKernelGGL((tp_mfma_kernel<0>), dim3(512), dim3(512), 0, stream,
                           node_attr, edge_index, edge_attr, edge_sh, w1, b1, w2, b2,
                           (unsigned short*)nullptr, (int*)nullptr, summed, counts);
        int fblk = (NNODES * 40 + 255) / 256;
        hipLaunchKernelGGL(finalize_kernel, dim3(fblk), dim3(256), 0, stream,
                           summed, counts, node_attr, out);
    }
}